// Round 18
// baseline (448.018 us; speedup 1.0000x reference)
//
#include <hip/hip_runtime.h>
#include <cstdint>
#include <cstddef>

// SwinBlock3D: LN1 -> roll(-1,-3,-3) -> window(2,7,7) attn (12 heads, rel-bias)
// -> proj + resid -> LN2 -> MLP(384->1536 gelu ->384) + resid.
// R18 = R17's wins (attn writes packed-A, proj on stream GEMM) + R17's loss
// reverted (LN2 back to standalone ln_pack2; mlp_fused = R15 version with
// gload16 packed-A staging -- in-kernel LN2 cost +22us via LDS bank conflicts
// and uncoalesced s1 reads).

typedef __bf16 bf16x8 __attribute__((ext_vector_type(8)));
typedef __bf16 bf16x4 __attribute__((ext_vector_type(4)));
typedef float f32x4 __attribute__((ext_vector_type(4)));

#define DIM 384
#define QKV_DIM 1152
#define HID 1536
#define NHEADS 12
#define NTOK 50176
#define NWIN 512

__device__ __forceinline__ void gload16(const void* g, void* s) {
  __builtin_amdgcn_global_load_lds(
      (const __attribute__((address_space(1))) void*)g,
      (__attribute__((address_space(3))) void*)s, 16, 0, 0);
}

// ---------------- prep kernels ----------------
__global__ __launch_bounds__(256) void build_tokmap_k(int* __restrict__ map) {
  int t = blockIdx.x * 256 + threadIdx.x;
  if (t >= NTOK) return;
  int win = t / 98, n = t - win * 98;
  int b = win >> 8, tw = (win >> 6) & 3, hw = (win >> 3) & 7, ww = win & 7;
  int dt = n / 49; int rem = n - dt * 49; int dh = rem / 7, dw = rem - dh * 7;
  int t0 = (tw * 2 + dt + 1) & 7;
  int h0 = hw * 7 + dh + 3; if (h0 >= 56) h0 -= 56;
  int w0 = ww * 7 + dw + 3; if (w0 >= 56) w0 -= 56;
  map[t] = ((b * 8 + t0) * 56 + h0) * 56 + w0;
}

__global__ __launch_bounds__(256) void expand_biasp_k(const float* __restrict__ table,
                                                      const int* __restrict__ rel,
                                                      float* __restrict__ out) {
  int e = blockIdx.x * 256 + threadIdx.x;
  if (e >= NHEADS * 49 * 256) return;
  int r = e & 3, l = (e >> 2) & 63;
  int rest = e >> 8;
  int ni = rest % 7, mi = (rest / 7) % 7, h = rest / 49;
  int i = mi * 16 + (l >> 4) * 4 + r;
  int j = ni * 16 + (l & 15);
  float v;
  if (j >= 98) v = -1e30f;
  else if (i >= 98) v = 0.f;
  else v = table[rel[i * 98 + j] * NHEADS + h];
  out[e] = v;
}

// 64-col-group fragment-stream pack (qkv/proj/fc1)
__global__ __launch_bounds__(256) void pack_w64_k(const float* __restrict__ W,
                                                  __bf16* __restrict__ WP,
                                                  int K, int N, int nk,
                                                  int scaleCols, float scale) {
  int idx = blockIdx.x * 256 + threadIdx.x;
  if (idx >= (K * N) >> 3) return;
  int l = idx & 63, f = (idx >> 6) & 7;
  int rest = idx >> 9, kt = rest % nk, cn = rest / nk;
  int n = f >> 1, kk = f & 1;
  int col = cn * 64 + n * 16 + (l & 15);
  int k0 = kt * 64 + (kk * 4 + (l >> 4)) * 8;
  float sc = (col < scaleCols) ? scale : 1.0f;
  bf16x8 v;
  #pragma unroll
  for (int j = 0; j < 8; ++j)
    v[j] = (__bf16)(W[(size_t)(k0 + j) * N + col] * sc);
  *(bf16x8*)(WP + (size_t)idx * 8) = v;
}

// 96-col-group pack for fused fc2
__global__ __launch_bounds__(256) void pack_w96_k(const float* __restrict__ W,
                                                  __bf16* __restrict__ WP) {
  int idx = blockIdx.x * 256 + threadIdx.x;
  if (idx >= (HID * DIM) >> 3) return;
  int l = idx & 63, n = (idx >> 6) % 6;
  int j8 = (idx / 384) % 48, w = idx / 18432;
  int col = w * 96 + n * 16 + (l & 15);
  int k0 = j8 * 32 + (l >> 4) * 8;
  bf16x8 v;
  #pragma unroll
  for (int j = 0; j < 8; ++j)
    v[j] = (__bf16)W[(size_t)(k0 + j) * DIM + col];
  *(bf16x8*)(WP + (size_t)idx * 8) = v;
}

__global__ __launch_bounds__(256) void scale_bias_k(const float* __restrict__ b,
                                                    float* __restrict__ out,
                                                    int n, int scaleCols, float scale) {
  int e = blockIdx.x * 256 + threadIdx.x;
  if (e >= n) return;
  out[e] = b[e] * (e < scaleCols ? scale : 1.0f);
}

// V^T via LDS transpose (R10)
__global__ __launch_bounds__(384) void vtrans_k(const __bf16* __restrict__ qkv,
                                                __bf16* __restrict__ vt) {
  __shared__ __align__(1024) char T[98304];
  int win = blockIdx.x, t = threadIdx.x;
  const __bf16* base = qkv + (size_t)win * 98 * QKV_DIM + 768 + t;
  #pragma unroll
  for (int c = 0; c < 16; ++c) {
    bf16x8 pk;
    #pragma unroll
    for (int e2 = 0; e2 < 8; ++e2) {
      int tok = c * 8 + e2;
      pk[e2] = (tok < 98) ? base[(size_t)tok * QKV_DIM] : (__bf16)0.f;
    }
    *(bf16x8*)(T + t * 256 + ((c ^ (t & 15)) << 4)) = pk;
  }
  __syncthreads();
  char* wb = (char*)(vt + (size_t)win * 49152);
  #pragma unroll
  for (int i = 0; i < 16; ++i) {
    int g = i * 6144 + t * 16;
    int row = g >> 8, p = (g >> 4) & 15;
    bf16x8 v = *(const bf16x8*)(T + row * 256 + (p << 4));
    int lc = p ^ (row & 15);
    *(bf16x8*)(wb + row * 256 + (lc << 4)) = v;
  }
}

// ---- layernorm writing PACKED A layout (LN1 and LN2) ----
template <typename T, bool MAP>
__global__ __launch_bounds__(256) void ln_pack_k(const T* __restrict__ x,
                                                 const float* __restrict__ g,
                                                 const float* __restrict__ bta,
                                                 __bf16* __restrict__ outp,
                                                 const int* __restrict__ map) {
  const int w = threadIdx.x >> 6, l = threadIdx.x & 63;
  const int tok = blockIdx.x * 32 + w * 8 + (l >> 3);
  const int src = MAP ? map[tok] : tok;
  const T* row = x + (size_t)src * DIM;
  const int o0 = l & 7;
  float v[6][8];
  float s = 0.f;
  #pragma unroll
  for (int j = 0; j < 6; ++j) {
    const int c = (o0 + 8 * j) * 8;
    if constexpr (sizeof(T) == 4) {
      f32x4 p0 = *(const f32x4*)(row + c);
      f32x4 p1 = *(const f32x4*)(row + c + 4);
      #pragma unroll
      for (int e = 0; e < 4; ++e) { v[j][e] = p0[e]; v[j][e + 4] = p1[e]; }
    } else {
      bf16x8 p = *(const bf16x8*)(row + c);
      #pragma unroll
      for (int e = 0; e < 8; ++e) v[j][e] = (float)p[e];
    }
    #pragma unroll
    for (int e = 0; e < 8; ++e) s += v[j][e];
  }
  s += __shfl_xor(s, 1, 64); s += __shfl_xor(s, 2, 64); s += __shfl_xor(s, 4, 64);
  const float mu = s * (1.f / DIM);
  float var = 0.f;
  #pragma unroll
  for (int j = 0; j < 6; ++j)
    #pragma unroll
    for (int e = 0; e < 8; ++e) { float d = v[j][e] - mu; var += d * d; }
  var += __shfl_xor(var, 1, 64); var += __shfl_xor(var, 2, 64); var += __shfl_xor(var, 4, 64);
  const float rs = rsqrtf(var * (1.f / DIM) + 1e-5f);
  const int mg = tok >> 6, m = (tok >> 4) & 3, lr = tok & 15;
  const int kk = o0 >> 2, lg = o0 & 3;
  __bf16* dst = outp + (size_t)mg * 24576 + (m * 2 + kk) * 512 + (lg * 16 + lr) * 8;
  #pragma unroll
  for (int j = 0; j < 6; ++j) {
    const int c = (o0 + 8 * j) * 8;
    f32x4 g0 = *(const f32x4*)(g + c), g1 = *(const f32x4*)(g + c + 4);
    f32x4 b0 = *(const f32x4*)(bta + c), b1 = *(const f32x4*)(bta + c + 4);
    bf16x8 ov;
    #pragma unroll
    for (int e = 0; e < 4; ++e) {
      ov[e] = (__bf16)((v[j][e] - mu) * rs * g0[e] + b0[e]);
      ov[e + 4] = (__bf16)((v[j][e + 4] - mu) * rs * g1[e] + b1[e]);
    }
    *(bf16x8*)(dst + (size_t)j * 4096) = ov;
  }
}

// ------ pure-register streaming GEMM (2-deep, R13-proven) -------------------
// EPI: 0 = +bias -> bf16 row-major (qkv)
//      1 = +bias + residf(x fp32) scattered via tokmap -> bf16 row-major (proj)
template <int EPI, int NK>
__global__ __launch_bounds__(256) void gemm_stream_k(const __bf16* __restrict__ AP,
                                                     const __bf16* __restrict__ WP,
                                                     const float* __restrict__ bias,
                                                     int N,
                                                     __bf16* __restrict__ outb,
                                                     const float* __restrict__ residf,
                                                     const int* __restrict__ tokmap) {
  __shared__ __align__(1024) char lds[32768];     // epilogue staging only
  const int tid = threadIdx.x;
  const int l = tid & 63, w = tid >> 6;
  const int lr = l & 15, lg = l >> 4;
  const int ntile = N >> 6;
  const int nwg = gridDim.x, qd = nwg >> 3, rm = nwg & 7;
  const int xcd = blockIdx.x & 7;
  const int wgid = (xcd < rm ? xcd * (qd + 1) : rm * (qd + 1) + (xcd - rm) * qd)
                   + (blockIdx.x >> 3);
  const int bm = wgid / ntile, bn = wgid - bm * ntile;
  const int mg = bm * 4 + w;
  const int m0 = mg << 6, n0 = bn << 6;
  const __bf16* pA = AP + (size_t)mg * (NK * 4096) + l * 8;
  const __bf16* pB = WP + (size_t)bn * (NK * 4096) + l * 8;

  bf16x8 a[2][8], b[2][8];
  f32x4 acc[4][4] = {};
  #pragma unroll
  for (int f = 0; f < 8; ++f) {
    a[0][f] = *(const bf16x8*)(pA + f * 512);
    b[0][f] = *(const bf16x8*)(pB + f * 512);
  }
  #pragma unroll
  for (int kt = 0; kt < NK; ++kt) {
    const int cur = kt & 1, nxt = cur ^ 1;
    if (kt < NK - 1) {
      const size_t ko = (size_t)(kt + 1) * 4096;
      #pragma unroll
      for (int f = 0; f < 8; ++f) {
        a[nxt][f] = *(const bf16x8*)(pA + ko + f * 512);
        b[nxt][f] = *(const bf16x8*)(pB + ko + f * 512);
      }
      asm volatile("s_waitcnt vmcnt(16)" ::: "memory");
    } else {
      asm volatile("s_waitcnt vmcnt(0)" ::: "memory");
    }
    __builtin_amdgcn_sched_barrier(0);
    __builtin_amdgcn_s_setprio(1);
    #pragma unroll
    for (int kk = 0; kk < 2; ++kk)
      #pragma unroll
      for (int m = 0; m < 4; ++m)
        #pragma unroll
        for (int n = 0; n < 4; ++n)   // swapped operands -> C^T fragment layout
          acc[m][n] = __builtin_amdgcn_mfma_f32_16x16x32_bf16(
              b[cur][n * 2 + kk], a[cur][m * 2 + kk], acc[m][n], 0, 0, 0);
    __builtin_amdgcn_s_setprio(0);
  }

  char* abuf = lds + (w << 13);
  #pragma unroll
  for (int m = 0; m < 4; ++m) {
    const int row = (m << 4) + lr;
    #pragma unroll
    for (int n = 0; n < 4; ++n) {
      const int gcol = n0 + (n << 4) + (lg << 2);
      f32x4 a4 = acc[m][n] + *(const f32x4*)(bias + gcol);
      bf16x4 c;
      #pragma unroll
      for (int r = 0; r < 4; ++r) c[r] = (__bf16)a4[r];
      const int ch = (n << 1) + (lg >> 1);
      *(bf16x4*)(abuf + (row << 7) + ((ch ^ (row & 7)) << 4) + ((lg & 1) << 3)) = c;
    }
  }
  asm volatile("s_waitcnt lgkmcnt(0)" ::: "memory");
  __builtin_amdgcn_sched_barrier(0);
  #pragma unroll
  for (int i = 0; i < 8; ++i) {
    const int row = (i << 3) + (l >> 3);
    const int p = (l & 7) ^ (row & 7);
    bf16x8 v = *(const bf16x8*)(abuf + (row << 7) + (p << 4));
    const int gcol = n0 + ((l & 7) << 3);
    if (EPI == 1) {
      const int dst = tokmap[m0 + row];
      const float* rp = residf + (size_t)dst * N + gcol;
      f32x4 r0 = *(const f32x4*)rp, r1 = *(const f32x4*)(rp + 4);
      bf16x8 c2;
      #pragma unroll
      for (int j = 0; j < 4; ++j) {
        c2[j] = (__bf16)(r0[j] + (float)v[j]);
        c2[j + 4] = (__bf16)(r1[j] + (float)v[j + 4]);
      }
      *(bf16x8*)(outb + (size_t)dst * N + gcol) = c2;
    } else {
      *(bf16x8*)(outb + (size_t)(m0 + row) * N + gcol) = v;
    }
  }
}

// ------ FUSED MLP (R15 version): fc1 + gelu + fc2 + residual ---------------
// Block = 64 tokens; packed A staged once via gload16; per super-iter j:
// fc1(j) barrier-free after fc2(j-1) -> barrier -> gelu h-write -> barrier ->
// fc2(j) with W2 t-tile register double-buffer.
__global__ __launch_bounds__(256, 2) void mlp_fused_k(const __bf16* __restrict__ AP,
                                                      const __bf16* __restrict__ W1P,
                                                      const float* __restrict__ b1,
                                                      const __bf16* __restrict__ W2P,
                                                      const float* __restrict__ b2,
                                                      const __bf16* __restrict__ s1,
                                                      float* __restrict__ outp) {
  __shared__ __align__(1024) char lds[81920];     // A 48KB | h 4x8KB
  const int tid = threadIdx.x, l = tid & 63, w = tid >> 6;
  const int lr = l & 15, lg = l >> 4;
  const int bid = (blockIdx.x & 7) * (gridDim.x >> 3) + (blockIdx.x >> 3);
  const int tok0 = bid << 6;

  const __bf16* APg = AP + (size_t)bid * 24576;
  #pragma unroll
  for (int i = 0; i < 12; ++i) {
    const int c = w * 12 + i;
    gload16(APg + c * 512 + l * 8, lds + c * 1024);
  }
  asm volatile("s_waitcnt vmcnt(0)" ::: "memory");
  asm volatile("s_barrier" ::: "memory");

  char* hbase = lds + 49152;
  char* hb = hbase + (w << 13);
  const __bf16* W2w = W2P + (size_t)w * 147456 + l * 8;   // w*48*6*512
  f32x4 acc2[4][6] = {};

#define LOADW2(dst, j, t)                                                      \
  { _Pragma("unroll")                                                          \
    for (int q_ = 0; q_ < 2; ++q_)                                             \
      _Pragma("unroll")                                                        \
      for (int n_ = 0; n_ < 6; ++n_)                                           \
        dst[q_ * 6 + n_] = *(const bf16x8*)(                                   \
            W2w + (size_t)(((j) * 8 + 2 * (t) + q_) * 6 + n_) * 512); }
#define FC2_STEP(T, BCUR, BNXT)                                                \
  {                                                                            \
    if ((T) < 3) LOADW2(BNXT, j, (T) + 1)                                      \
    bf16x8 ah[4][2];                                                           \
    const char* ht = hbase + ((T) << 13);                                      \
    _Pragma("unroll")                                                          \
    for (int m_ = 0; m_ < 4; ++m_)                                             \
      _Pragma("unroll")                                                        \
      for (int q_ = 0; q_ < 2; ++q_) {                                         \
        const int r_ = (m_ << 4) + lr, ck_ = (q_ << 2) + lg;                   \
        ah[m_][q_] = *(const bf16x8*)(ht + (r_ << 7) + ((ck_ ^ (r_ & 7)) << 4)); \
      }                                                                        \
    __builtin_amdgcn_s_setprio(1);                                             \
    _Pragma("unroll")                                                          \
    for (int q_ = 0; q_ < 2; ++q_)                                             \
      _Pragma("unroll")                                                        \
      for (int m_ = 0; m_ < 4; ++m_)                                           \
        _Pragma("unroll")                                                      \
        for (int n_ = 0; n_ < 6; ++n_)                                         \
          acc2[m_][n_] = __builtin_amdgcn_mfma_f32_16x16x32_bf16(              \
              BCUR[q_ * 6 + n_], ah[m_][q_], acc2[m_][n_], 0, 0, 0);           \
    __builtin_amdgcn_s_setprio(0);                                             \
  }

  for (int j = 0; j < 6; ++j) {
    const int g = j * 4 + w;
    const __bf16* W1g = W1P + (size_t)g * 24576 + l * 8;
    f32x4 acc1[4][4] = {};
    #pragma unroll
    for (int kt = 0; kt < 6; ++kt) {
      bf16x8 a[4][2], b[8];
      #pragma unroll
      for (int f = 0; f < 8; ++f)
        b[f] = *(const bf16x8*)(W1g + kt * 4096 + f * 512);
      #pragma unroll
      for (int m = 0; m < 4; ++m)
        #pragma unroll
        for (int kk = 0; kk < 2; ++kk)
          a[m][kk] = *(const bf16x8*)(lds + (kt * 8 + m * 2 + kk) * 1024 + l * 16);
      __builtin_amdgcn_s_setprio(1);
      #pragma unroll
      for (int kk = 0; kk < 2; ++kk)
        #pragma unroll
        for (int m = 0; m < 4; ++m)
          #pragma unroll
          for (int n = 0; n < 4; ++n)
            acc1[m][n] = __builtin_amdgcn_mfma_f32_16x16x32_bf16(
                b[n * 2 + kk], a[m][kk], acc1[m][n], 0, 0, 0);
      __builtin_amdgcn_s_setprio(0);
    }
    asm volatile("s_barrier" ::: "memory");     // protect h(j-1) readers
    #pragma unroll
    for (int m = 0; m < 4; ++m) {
      const int row = (m << 4) + lr;
      #pragma unroll
      for (int n = 0; n < 4; ++n) {
        f32x4 a4 = acc1[m][n] + *(const f32x4*)(b1 + g * 64 + (n << 4) + (lg << 2));
        bf16x4 c;
        #pragma unroll
        for (int r = 0; r < 4; ++r) {
          float vv = a4[r];
          float y = vv * (1.0f + 0.044715f * vv * vv);
          c[r] = (__bf16)(vv / (1.0f + __expf(-1.5957691216057308f * y)));
        }
        const int ch = (n << 1) + (lg >> 1);
        *(bf16x4*)(hb + (row << 7) + ((ch ^ (row & 7)) << 4) + ((lg & 1) << 3)) = c;
      }
    }
    asm volatile("s_waitcnt lgkmcnt(0)" ::: "memory");
    __builtin_amdgcn_sched_barrier(0);
    asm volatile("s_barrier" ::: "memory");     // h(j) visible
    {
      bf16x8 bhA[12], bhB[12];
      LOADW2(bhA, j, 0)
      FC2_STEP(0, bhA, bhB)
      FC2_STEP(1, bhB, bhA)
      FC2_STEP(2, bhA, bhB)
      FC2_STEP(3, bhB, bhA)
    }
  }
#undef FC2_STEP
#undef LOADW2

  // epilogue: +b2 +s1(bf16) -> fp32 row-major
  const int col0 = w * 96;
  #pragma unroll
  for (int m = 0; m < 4; ++m) {
    const int grow = tok0 + (m << 4) + lr;
    #pragma unroll
    for (int n = 0; n < 6; ++n) {
      const int gcol = col0 + (n << 4) + (lg << 2);
      f32x4 a4 = acc2[m][n] + *(const f32x4*)(b2 + gcol);
      bf16x4 sv = *(const bf16x4*)(s1 + (size_t)grow * DIM + gcol);
      f32x4 o;
      #pragma unroll
      for (int r = 0; r < 4; ++r) o[r] = a4[r] + (float)sv[r];
      *(f32x4*)(outp + (size_t)grow * DIM + gcol) = o;
    }
  }
}

// ---------------- window attention: writes PACKED-A layout for proj --------
__global__ __launch_bounds__(64) void attn_k(const __bf16* __restrict__ qkv,
                                             const __bf16* __restrict__ vt,
                                             const float* __restrict__ pb,
                                             __bf16* __restrict__ outp) {
  __shared__ __align__(1024) char P[4096];
  const int l = threadIdx.x, lr = l & 15, lg = l >> 4;
  const int bid = blockIdx.x;
  const int xc = bid & 7, kk = bid >> 3;
  const int wh = (kk / 7) * 8 + xc, mi = kk % 7;
  const int win = wh / NHEADS, h = wh - win * NHEADS;
  const size_t wbase = (size_t)win * 98 * QKV_DIM;
  const __bf16* qb = qkv + wbase + h * 32;
  const __bf16* kb = qb + 384;
  const bf16x8 z8 = {};
  const f32x4 fz = {};

  bf16x8 kf[7];
  #pragma unroll
  for (int ni = 0; ni < 7; ++ni) {
    int tok = ni * 16 + lr;
    kf[ni] = (tok < 98) ? *(const bf16x8*)(kb + (size_t)tok * QKV_DIM + lg * 8) : z8;
  }
  int qt = mi * 16 + lr;
  bf16x8 qf = (qt < 98) ? *(const bf16x8*)(qb + (size_t)qt * QKV_DIM + lg * 8) : z8;
  const f32x4* pbp = (const f32x4*)pb + (size_t)((h * 7 + mi) * 7) * 64 + l;
  f32x4 bv[7];
  #pragma unroll
  for (int ni = 0; ni < 7; ++ni) bv[ni] = pbp[ni * 64];

  f32x4 s[7];
  #pragma unroll
  for (int ni = 0; ni < 7; ++ni)
    s[ni] = __builtin_amdgcn_mfma_f32_16x16x32_bf16(qf, kf[ni], fz, 0, 0, 0);

  if (l < 32) {
    int row = l >> 1, c = 14 + (l & 1);
    *(f32x4*)(P + row * 256 + ((c ^ (row & 7)) << 4)) = fz;
  }

  #pragma unroll
  for (int r = 0; r < 4; ++r) {
    float mx = -1e30f;
    #pragma unroll
    for (int ni = 0; ni < 7; ++ni) {
      float vv = s[ni][r] + bv[ni][r];
      s[ni][r] = vv;
      mx = fmaxf(mx, vv);
    }
    #pragma unroll
    for (int m2 = 1; m2 < 16; m2 <<= 1) mx = fmaxf(mx, __shfl_xor(mx, m2, 64));
    float sum = 0.f;
    #pragma unroll
    for (int ni = 0; ni < 7; ++ni) { float p = __expf(s[ni][r] - mx); s[ni][r] = p; sum += p; }
    #pragma unroll
    for (int m2 = 1; m2 < 16; m2 <<= 1) sum += __shfl_xor(sum, m2, 64);
    float inv = 1.0f / sum;
    int il = lg * 4 + r;
    #pragma unroll
    for (int ni = 0; ni < 7; ++ni) {
      int j = ni * 16 + lr;
      *(__bf16*)(P + il * 256 + (((j >> 3) ^ (il & 7)) << 4) + ((j & 7) << 1)) =
          (__bf16)(s[ni][r] * inv);
    }
  }
  __syncthreads();

  bf16x8 pa[4];
  #pragma unroll
  for (int ks = 0; ks < 4; ++ks) {
    int ck = ks * 4 + lg;
    pa[ks] = *(const bf16x8*)(P + lr * 256 + ((ck ^ (lr & 7)) << 4));
  }
  const __bf16* vrow = vt + ((size_t)wh * 32) * 128;
  f32x4 oo[2];
  #pragma unroll
  for (int nf = 0; nf < 2; ++nf) {
    int d = nf * 16 + lr;
    f32x4 o = fz;
    #pragma unroll
    for (int ks = 0; ks < 4; ++ks) {
      bf16x8 vb = *(const bf16x8*)(vrow + (size_t)d * 128 + ks * 32 + lg * 8);
      o = __builtin_amdgcn_mfma_f32_16x16x32_bf16(pa[ks], vb, o, 0, 0, 0);
    }
    oo[nf] = o;
  }
  #pragma unroll
  for (int nf = 0; nf < 2; ++nf)
    #pragma unroll
    for (int r = 0; r < 4; ++r)
      *(__bf16*)(P + (lg * 4 + r) * 64 + (((nf << 4) + lr) << 1)) = (__bf16)oo[nf][r];
  asm volatile("s_waitcnt lgkmcnt(0)" ::: "memory");
  __builtin_amdgcn_sched_barrier(0);
  {
    const int row = l >> 2;
    bf16x8 v = *(const bf16x8*)(P + row * 64 + ((l & 3) << 4));
    const int tok = mi * 16 + row;
    if (tok < 98) {
      const int tg = win * 98 + tok;                 // global window-major token
      const int o = (h << 2) + (l & 3);              // feature octet
      const int mg2 = tg >> 6, m2 = (tg >> 4) & 3, lr2 = tg & 15;
      const int kt = o >> 3, kk2 = (o >> 2) & 1, lg2 = o & 3;
      *(bf16x8*)(outp + (size_t)mg2 * 24576 +
                 ((size_t)((kt * 8 + m2 * 2 + kk2) * 64 + (lg2 << 4) + lr2)) * 8) = v;
    }
  }
}

// ---------------- launch ----------------
extern "C" void kernel_launch(void* const* d_in, const int* in_sizes, int n_in,
                              void* d_out, int out_size, void* d_ws, size_t ws_size,
                              hipStream_t stream) {
  const float* x      = (const float*)d_in[0];
  const float* n1g    = (const float*)d_in[1];
  const float* n1b    = (const float*)d_in[2];
  const float* qkv_w  = (const float*)d_in[3];
  const float* qkv_b  = (const float*)d_in[4];
  const float* proj_w = (const float*)d_in[5];
  const float* proj_b = (const float*)d_in[6];
  const float* btab   = (const float*)d_in[7];
  const float* n2g    = (const float*)d_in[8];
  const float* n2b    = (const float*)d_in[9];
  const float* fc1_w  = (const float*)d_in[10];
  const float* fc1_b  = (const float*)d_in[11];
  const float* fc2_w  = (const float*)d_in[12];
  const float* fc2_b  = (const float*)d_in[13];
  const int*   relidx = (const int*)d_in[14];
  float* outp = (float*)d_out;
  (void)in_sizes; (void)n_in; (void)out_size; (void)ws_size;

  char* ws = (char*)d_ws;
  size_t off = 0;
  auto alloc = [&](size_t bytes) {
    char* p = ws + off;
    off = (off + bytes + 255) & ~(size_t)255;
    return p;
  };
  int*    tokmap  = (int*)alloc((size_t)NTOK * 4);
  float*  biasex  = (float*)alloc((size_t)NHEADS * 49 * 256 * 4);
  __bf16* wqkvP   = (__bf16*)alloc((size_t)QKV_DIM * DIM * 2);
  __bf16* wprojP  = (__bf16*)alloc((size_t)DIM * DIM * 2);
  __bf16* wfc1P   = (__bf16*)alloc((size_t)HID * DIM * 2);
  __bf16* wfc2P   = (__bf16*)alloc((size_t)DIM * HID * 2);
  float*  qkvbS   = (float*)alloc((size_t)QKV_DIM * 4);
  __bf16* tokens  = (__bf16*)alloc((size_t)NTOK * DIM * 2);  // LN1-packed, later attn-packed
  __bf16* qkvbuf  = (__bf16*)alloc((size_t)NTOK * HID * 2);  // qkv row-major
  __bf16* s1      = (__bf16*)alloc((size_t)NTOK * DIM * 2);  // x + attn-proj, bf16
  __bf16* tokens2 = (__bf16*)alloc((size_t)NTOK * DIM * 2);  // LN2-packed
  __bf16* vt = (__bf16*)d_out;    // scratch in d_out until the fused MLP writes it

  const float scale = 0.17677669529663687f;  // 1/sqrt(32)

  build_tokmap_k<<<NTOK / 256, 256, 0, stream>>>(tokmap);
  expand_biasp_k<<<(NHEADS * 49 * 256) / 256, 256, 0, stream>>>(btab, relidx, biasex);
  pack_w64_k<<<(DIM * QKV_DIM / 8) / 256, 256, 0, stream>>>(qkv_w, wqkvP, DIM, QKV_DIM, 6, DIM, scale);
  pack_w64_k<<<(DIM * DIM / 8) / 256, 256, 0, stream>>>(proj_w, wprojP, DIM, DIM, 6, 0, 1.0f);
  pack_w64_k<<<(DIM * HID / 8) / 256, 256, 0, stream>>>(fc1_w, wfc1P, DIM, HID, 6, 0, 1.0f);
  pack_w96_k<<<(HID * DIM / 8) / 256, 256, 0, stream>>>(fc2_w, wfc2P);
  scale_bias_k<<<(QKV_DIM + 255) / 256, 256, 0, stream>>>(qkv_b, qkvbS, QKV_DIM, DIM, scale);

  ln_pack_k<float, true><<<NTOK / 32, 256, 0, stream>>>(x, n1g, n1b, tokens, tokmap);
  gemm_stream_k<0, 6><<<(NTOK / 256) * (QKV_DIM / 64), 256, 0, stream>>>(
      tokens, wqkvP, qkvbS, QKV_DIM, qkvbuf, nullptr, nullptr);
  vtrans_k<<<NWIN, 384, 0, stream>>>(qkvbuf, vt);
  attn_k<<<NWIN * NHEADS * 7, 64, 0, stream>>>(qkvbuf, vt, biasex, tokens);
  gemm_stream_k<1, 6><<<(NTOK / 256) * (DIM / 64), 256, 0, stream>>>(
      tokens, wprojP, proj_b, DIM, s1, x, tokmap);
  ln_pack_k<__bf16, false><<<NTOK / 32, 256, 0, stream>>>(s1, n2g, n2b, tokens2, nullptr);
  mlp_fused_k<<<NTOK / 64, 256, 0, stream>>>(
      tokens2, wfc1P, fc1_b, wfc2P, fc2_b, s1, outp);
}

// Round 19
// 441.125 us; speedup vs baseline: 1.0156x; 1.0156x over previous
//
#include <hip/hip_runtime.h>
#include <cstdint>
#include <cstddef>

// SwinBlock3D: LN1 -> roll(-1,-3,-3) -> window(2,7,7) attn (12 heads, rel-bias)
// -> proj + resid -> LN2 -> MLP(384->1536 gelu ->384) + resid.
// R19 = exact restoration of R17, the best-measured configuration (442.5us):
//  - LN1 -> packed-A; qkv + proj on the pure-register stream GEMM
//  - attn writes packed-A layout directly (proj consumes it)
//  - mlp_fused: in-kernel LN2 prologue + fc1/gelu/fc2/residual, 64-token
//    blocks, h never leaves LDS, W2 t-tile register double-buffer
// R18's split-LN2 variant measured 448.0 (graph serialization of the extra
// dispatch outweighs the in-kernel LN's bank conflicts) -> reverted.

typedef __bf16 bf16x8 __attribute__((ext_vector_type(8)));
typedef __bf16 bf16x4 __attribute__((ext_vector_type(4)));
typedef float f32x4 __attribute__((ext_vector_type(4)));

#define DIM 384
#define QKV_DIM 1152
#define HID 1536
#define NHEADS 12
#define NTOK 50176
#define NWIN 512

__device__ __forceinline__ void gload16(const void* g, void* s) {
  __builtin_amdgcn_global_load_lds(
      (const __attribute__((address_space(1))) void*)g,
      (__attribute__((address_space(3))) void*)s, 16, 0, 0);
}

// ---------------- prep kernels ----------------
__global__ __launch_bounds__(256) void build_tokmap_k(int* __restrict__ map) {
  int t = blockIdx.x * 256 + threadIdx.x;
  if (t >= NTOK) return;
  int win = t / 98, n = t - win * 98;
  int b = win >> 8, tw = (win >> 6) & 3, hw = (win >> 3) & 7, ww = win & 7;
  int dt = n / 49; int rem = n - dt * 49; int dh = rem / 7, dw = rem - dh * 7;
  int t0 = (tw * 2 + dt + 1) & 7;
  int h0 = hw * 7 + dh + 3; if (h0 >= 56) h0 -= 56;
  int w0 = ww * 7 + dw + 3; if (w0 >= 56) w0 -= 56;
  map[t] = ((b * 8 + t0) * 56 + h0) * 56 + w0;
}

__global__ __launch_bounds__(256) void expand_biasp_k(const float* __restrict__ table,
                                                      const int* __restrict__ rel,
                                                      float* __restrict__ out) {
  int e = blockIdx.x * 256 + threadIdx.x;
  if (e >= NHEADS * 49 * 256) return;
  int r = e & 3, l = (e >> 2) & 63;
  int rest = e >> 8;
  int ni = rest % 7, mi = (rest / 7) % 7, h = rest / 49;
  int i = mi * 16 + (l >> 4) * 4 + r;
  int j = ni * 16 + (l & 15);
  float v;
  if (j >= 98) v = -1e30f;
  else if (i >= 98) v = 0.f;
  else v = table[rel[i * 98 + j] * NHEADS + h];
  out[e] = v;
}

// 64-col-group fragment-stream pack (qkv/proj/fc1)
__global__ __launch_bounds__(256) void pack_w64_k(const float* __restrict__ W,
                                                  __bf16* __restrict__ WP,
                                                  int K, int N, int nk,
                                                  int scaleCols, float scale) {
  int idx = blockIdx.x * 256 + threadIdx.x;
  if (idx >= (K * N) >> 3) return;
  int l = idx & 63, f = (idx >> 6) & 7;
  int rest = idx >> 9, kt = rest % nk, cn = rest / nk;
  int n = f >> 1, kk = f & 1;
  int col = cn * 64 + n * 16 + (l & 15);
  int k0 = kt * 64 + (kk * 4 + (l >> 4)) * 8;
  float sc = (col < scaleCols) ? scale : 1.0f;
  bf16x8 v;
  #pragma unroll
  for (int j = 0; j < 8; ++j)
    v[j] = (__bf16)(W[(size_t)(k0 + j) * N + col] * sc);
  *(bf16x8*)(WP + (size_t)idx * 8) = v;
}

// 96-col-group pack for fused fc2
__global__ __launch_bounds__(256) void pack_w96_k(const float* __restrict__ W,
                                                  __bf16* __restrict__ WP) {
  int idx = blockIdx.x * 256 + threadIdx.x;
  if (idx >= (HID * DIM) >> 3) return;
  int l = idx & 63, n = (idx >> 6) % 6;
  int j8 = (idx / 384) % 48, w = idx / 18432;
  int col = w * 96 + n * 16 + (l & 15);
  int k0 = j8 * 32 + (l >> 4) * 8;
  bf16x8 v;
  #pragma unroll
  for (int j = 0; j < 8; ++j)
    v[j] = (__bf16)W[(size_t)(k0 + j) * DIM + col];
  *(bf16x8*)(WP + (size_t)idx * 8) = v;
}

__global__ __launch_bounds__(256) void scale_bias_k(const float* __restrict__ b,
                                                    float* __restrict__ out,
                                                    int n, int scaleCols, float scale) {
  int e = blockIdx.x * 256 + threadIdx.x;
  if (e >= n) return;
  out[e] = b[e] * (e < scaleCols ? scale : 1.0f);
}

// V^T via LDS transpose (R10)
__global__ __launch_bounds__(384) void vtrans_k(const __bf16* __restrict__ qkv,
                                                __bf16* __restrict__ vt) {
  __shared__ __align__(1024) char T[98304];
  int win = blockIdx.x, t = threadIdx.x;
  const __bf16* base = qkv + (size_t)win * 98 * QKV_DIM + 768 + t;
  #pragma unroll
  for (int c = 0; c < 16; ++c) {
    bf16x8 pk;
    #pragma unroll
    for (int e2 = 0; e2 < 8; ++e2) {
      int tok = c * 8 + e2;
      pk[e2] = (tok < 98) ? base[(size_t)tok * QKV_DIM] : (__bf16)0.f;
    }
    *(bf16x8*)(T + t * 256 + ((c ^ (t & 15)) << 4)) = pk;
  }
  __syncthreads();
  char* wb = (char*)(vt + (size_t)win * 49152);
  #pragma unroll
  for (int i = 0; i < 16; ++i) {
    int g = i * 6144 + t * 16;
    int row = g >> 8, p = (g >> 4) & 15;
    bf16x8 v = *(const bf16x8*)(T + row * 256 + (p << 4));
    int lc = p ^ (row & 15);
    *(bf16x8*)(wb + row * 256 + (lc << 4)) = v;
  }
}

// ---- layernorm writing PACKED A layout (LN1 only) ----
template <typename T, bool MAP>
__global__ __launch_bounds__(256) void ln_pack_k(const T* __restrict__ x,
                                                 const float* __restrict__ g,
                                                 const float* __restrict__ bta,
                                                 __bf16* __restrict__ outp,
                                                 const int* __restrict__ map) {
  const int w = threadIdx.x >> 6, l = threadIdx.x & 63;
  const int tok = blockIdx.x * 32 + w * 8 + (l >> 3);
  const int src = MAP ? map[tok] : tok;
  const T* row = x + (size_t)src * DIM;
  const int o0 = l & 7;
  float v[6][8];
  float s = 0.f;
  #pragma unroll
  for (int j = 0; j < 6; ++j) {
    const int c = (o0 + 8 * j) * 8;
    if constexpr (sizeof(T) == 4) {
      f32x4 p0 = *(const f32x4*)(row + c);
      f32x4 p1 = *(const f32x4*)(row + c + 4);
      #pragma unroll
      for (int e = 0; e < 4; ++e) { v[j][e] = p0[e]; v[j][e + 4] = p1[e]; }
    } else {
      bf16x8 p = *(const bf16x8*)(row + c);
      #pragma unroll
      for (int e = 0; e < 8; ++e) v[j][e] = (float)p[e];
    }
    #pragma unroll
    for (int e = 0; e < 8; ++e) s += v[j][e];
  }
  s += __shfl_xor(s, 1, 64); s += __shfl_xor(s, 2, 64); s += __shfl_xor(s, 4, 64);
  const float mu = s * (1.f / DIM);
  float var = 0.f;
  #pragma unroll
  for (int j = 0; j < 6; ++j)
    #pragma unroll
    for (int e = 0; e < 8; ++e) { float d = v[j][e] - mu; var += d * d; }
  var += __shfl_xor(var, 1, 64); var += __shfl_xor(var, 2, 64); var += __shfl_xor(var, 4, 64);
  const float rs = rsqrtf(var * (1.f / DIM) + 1e-5f);
  const int mg = tok >> 6, m = (tok >> 4) & 3, lr = tok & 15;
  const int kk = o0 >> 2, lg = o0 & 3;
  __bf16* dst = outp + (size_t)mg * 24576 + (m * 2 + kk) * 512 + (lg * 16 + lr) * 8;
  #pragma unroll
  for (int j = 0; j < 6; ++j) {
    const int c = (o0 + 8 * j) * 8;
    f32x4 g0 = *(const f32x4*)(g + c), g1 = *(const f32x4*)(g + c + 4);
    f32x4 b0 = *(const f32x4*)(bta + c), b1 = *(const f32x4*)(bta + c + 4);
    bf16x8 ov;
    #pragma unroll
    for (int e = 0; e < 4; ++e) {
      ov[e] = (__bf16)((v[j][e] - mu) * rs * g0[e] + b0[e]);
      ov[e + 4] = (__bf16)((v[j][e + 4] - mu) * rs * g1[e] + b1[e]);
    }
    *(bf16x8*)(dst + (size_t)j * 4096) = ov;
  }
}

// ------ pure-register streaming GEMM (2-deep, R13-proven) -------------------
// EPI: 0 = +bias -> bf16 row-major (qkv)
//      1 = +bias + residf(x fp32) scattered via tokmap -> bf16 row-major (proj)
template <int EPI, int NK>
__global__ __launch_bounds__(256) void gemm_stream_k(const __bf16* __restrict__ AP,
                                                     const __bf16* __restrict__ WP,
                                                     const float* __restrict__ bias,
                                                     int N,
                                                     __bf16* __restrict__ outb,
                                                     const float* __restrict__ residf,
                                                     const int* __restrict__ tokmap) {
  __shared__ __align__(1024) char lds[32768];     // epilogue staging only
  const int tid = threadIdx.x;
  const int l = tid & 63, w = tid >> 6;
  const int lr = l & 15, lg = l >> 4;
  const int ntile = N >> 6;
  const int nwg = gridDim.x, qd = nwg >> 3, rm = nwg & 7;
  const int xcd = blockIdx.x & 7;
  const int wgid = (xcd < rm ? xcd * (qd + 1) : rm * (qd + 1) + (xcd - rm) * qd)
                   + (blockIdx.x >> 3);
  const int bm = wgid / ntile, bn = wgid - bm * ntile;
  const int mg = bm * 4 + w;
  const int m0 = mg << 6, n0 = bn << 6;
  const __bf16* pA = AP + (size_t)mg * (NK * 4096) + l * 8;
  const __bf16* pB = WP + (size_t)bn * (NK * 4096) + l * 8;

  bf16x8 a[2][8], b[2][8];
  f32x4 acc[4][4] = {};
  #pragma unroll
  for (int f = 0; f < 8; ++f) {
    a[0][f] = *(const bf16x8*)(pA + f * 512);
    b[0][f] = *(const bf16x8*)(pB + f * 512);
  }
  #pragma unroll
  for (int kt = 0; kt < NK; ++kt) {
    const int cur = kt & 1, nxt = cur ^ 1;
    if (kt < NK - 1) {
      const size_t ko = (size_t)(kt + 1) * 4096;
      #pragma unroll
      for (int f = 0; f < 8; ++f) {
        a[nxt][f] = *(const bf16x8*)(pA + ko + f * 512);
        b[nxt][f] = *(const bf16x8*)(pB + ko + f * 512);
      }
      asm volatile("s_waitcnt vmcnt(16)" ::: "memory");
    } else {
      asm volatile("s_waitcnt vmcnt(0)" ::: "memory");
    }
    __builtin_amdgcn_sched_barrier(0);
    __builtin_amdgcn_s_setprio(1);
    #pragma unroll
    for (int kk = 0; kk < 2; ++kk)
      #pragma unroll
      for (int m = 0; m < 4; ++m)
        #pragma unroll
        for (int n = 0; n < 4; ++n)   // swapped operands -> C^T fragment layout
          acc[m][n] = __builtin_amdgcn_mfma_f32_16x16x32_bf16(
              b[cur][n * 2 + kk], a[cur][m * 2 + kk], acc[m][n], 0, 0, 0);
    __builtin_amdgcn_s_setprio(0);
  }

  char* abuf = lds + (w << 13);
  #pragma unroll
  for (int m = 0; m < 4; ++m) {
    const int row = (m << 4) + lr;
    #pragma unroll
    for (int n = 0; n < 4; ++n) {
      const int gcol = n0 + (n << 4) + (lg << 2);
      f32x4 a4 = acc[m][n] + *(const f32x4*)(bias + gcol);
      bf16x4 c;
      #pragma unroll
      for (int r = 0; r < 4; ++r) c[r] = (__bf16)a4[r];
      const int ch = (n << 1) + (lg >> 1);
      *(bf16x4*)(abuf + (row << 7) + ((ch ^ (row & 7)) << 4) + ((lg & 1) << 3)) = c;
    }
  }
  asm volatile("s_waitcnt lgkmcnt(0)" ::: "memory");
  __builtin_amdgcn_sched_barrier(0);
  #pragma unroll
  for (int i = 0; i < 8; ++i) {
    const int row = (i << 3) + (l >> 3);
    const int p = (l & 7) ^ (row & 7);
    bf16x8 v = *(const bf16x8*)(abuf + (row << 7) + (p << 4));
    const int gcol = n0 + ((l & 7) << 3);
    if (EPI == 1) {
      const int dst = tokmap[m0 + row];
      const float* rp = residf + (size_t)dst * N + gcol;
      f32x4 r0 = *(const f32x4*)rp, r1 = *(const f32x4*)(rp + 4);
      bf16x8 c2;
      #pragma unroll
      for (int j = 0; j < 4; ++j) {
        c2[j] = (__bf16)(r0[j] + (float)v[j]);
        c2[j + 4] = (__bf16)(r1[j] + (float)v[j + 4]);
      }
      *(bf16x8*)(outb + (size_t)dst * N + gcol) = c2;
    } else {
      *(bf16x8*)(outb + (size_t)(m0 + row) * N + gcol) = v;
    }
  }
}

// ------ FUSED MLP v3: LN2 + fc1 + gelu + fc2 + residual. Block = 64 tokens.
// Prologue: in-kernel LN2 of 64 s1 rows -> packed A in LDS (4 lanes/row).
// Then R15 schedule: per super-iter j, fc1(j) (barrier-free after fc2(j-1)),
// barrier, gelu h-write, barrier, fc2(j) with W2 t-tile register dbuf.
__global__ __launch_bounds__(256, 2) void mlp_fused_k(const __bf16* __restrict__ s1,
                                                      const float* __restrict__ g2,
                                                      const float* __restrict__ bt2,
                                                      const __bf16* __restrict__ W1P,
                                                      const float* __restrict__ b1,
                                                      const __bf16* __restrict__ W2P,
                                                      const float* __restrict__ b2,
                                                      float* __restrict__ outp) {
  __shared__ __align__(1024) char lds[81920];     // A 48KB | h 4x8KB
  const int tid = threadIdx.x, l = tid & 63, w = tid >> 6;
  const int lr = l & 15, lg = l >> 4;
  const int bid = (blockIdx.x & 7) * (gridDim.x >> 3) + (blockIdx.x >> 3);
  const int tok0 = bid << 6;

  // ---- LN2 of this block's 64 s1 rows -> packed LDS (A region) ----
  {
    const int rloc = (w << 4) + (l >> 2);     // local token 0..63
    const int p = l & 3;
    const __bf16* srow = s1 + (size_t)(tok0 + rloc) * DIM;
    float vv[12][8];
    float s = 0.f;
    #pragma unroll
    for (int j = 0; j < 12; ++j) {
      const int o = (j << 2) + p;             // feature octet
      bf16x8 pk = *(const bf16x8*)(srow + (o << 3));
      #pragma unroll
      for (int e = 0; e < 8; ++e) { vv[j][e] = (float)pk[e]; s += vv[j][e]; }
    }
    s += __shfl_xor(s, 1, 64); s += __shfl_xor(s, 2, 64);
    const float mu = s * (1.f / DIM);
    float var = 0.f;
    #pragma unroll
    for (int j = 0; j < 12; ++j)
      #pragma unroll
      for (int e = 0; e < 8; ++e) { float d = vv[j][e] - mu; var += d * d; }
    var += __shfl_xor(var, 1, 64); var += __shfl_xor(var, 2, 64);
    const float rs = rsqrtf(var * (1.f / DIM) + 1e-5f);
    const int m2 = rloc >> 4, lr2 = rloc & 15;   // m2 == w
    #pragma unroll
    for (int j = 0; j < 12; ++j) {
      const int o = (j << 2) + p;
      const int kt = o >> 3, kk2 = (o >> 2) & 1, lg2 = o & 3;
      f32x4 g0 = *(const f32x4*)(g2 + (o << 3));
      f32x4 g1 = *(const f32x4*)(g2 + (o << 3) + 4);
      f32x4 b0 = *(const f32x4*)(bt2 + (o << 3));
      f32x4 b1 = *(const f32x4*)(bt2 + (o << 3) + 4);
      bf16x8 ov;
      #pragma unroll
      for (int e = 0; e < 4; ++e) {
        ov[e] = (__bf16)((vv[j][e] - mu) * rs * g0[e] + b0[e]);
        ov[e + 4] = (__bf16)((vv[j][e + 4] - mu) * rs * g1[e] + b1[e]);
      }
      *(bf16x8*)(lds + (kt * 8 + m2 * 2 + kk2) * 1024 + ((lg2 << 4) + lr2) * 16) = ov;
    }
  }
  __syncthreads();

  char* hbase = lds + 49152;
  char* hb = hbase + (w << 13);
  const __bf16* W2w = W2P + (size_t)w * 147456 + l * 8;   // w*48*6*512
  f32x4 acc2[4][6] = {};

#define LOADW2(dst, j, t)                                                      \
  { _Pragma("unroll")                                                          \
    for (int q_ = 0; q_ < 2; ++q_)                                             \
      _Pragma("unroll")                                                        \
      for (int n_ = 0; n_ < 6; ++n_)                                           \
        dst[q_ * 6 + n_] = *(const bf16x8*)(                                   \
            W2w + (size_t)(((j) * 8 + 2 * (t) + q_) * 6 + n_) * 512); }
#define FC2_STEP(T, BCUR, BNXT)                                                \
  {                                                                            \
    if ((T) < 3) LOADW2(BNXT, j, (T) + 1)                                      \
    bf16x8 ah[4][2];                                                           \
    const char* ht = hbase + ((T) << 13);                                      \
    _Pragma("unroll")                                                          \
    for (int m_ = 0; m_ < 4; ++m_)                                             \
      _Pragma("unroll")                                                        \
      for (int q_ = 0; q_ < 2; ++q_) {                                         \
        const int r_ = (m_ << 4) + lr, ck_ = (q_ << 2) + lg;                   \
        ah[m_][q_] = *(const bf16x8*)(ht + (r_ << 7) + ((ck_ ^ (r_ & 7)) << 4)); \
      }                                                                        \
    __builtin_amdgcn_s_setprio(1);                                             \
    _Pragma("unroll")                                                          \
    for (int q_ = 0; q_ < 2; ++q_)                                             \
      _Pragma("unroll")                                                        \
      for (int m_ = 0; m_ < 4; ++m_)                                           \
        _Pragma("unroll")                                                      \
        for (int n_ = 0; n_ < 6; ++n_)                                         \
          acc2[m_][n_] = __builtin_amdgcn_mfma_f32_16x16x32_bf16(              \
              BCUR[q_ * 6 + n_], ah[m_][q_], acc2[m_][n_], 0, 0, 0);           \
    __builtin_amdgcn_s_setprio(0);                                             \
  }

  for (int j = 0; j < 6; ++j) {
    const int g = j * 4 + w;
    const __bf16* W1g = W1P + (size_t)g * 24576 + l * 8;
    f32x4 acc1[4][4] = {};
    #pragma unroll
    for (int kt = 0; kt < 6; ++kt) {
      bf16x8 a[4][2], b[8];
      #pragma unroll
      for (int f = 0; f < 8; ++f)
        b[f] = *(const bf16x8*)(W1g + kt * 4096 + f * 512);
      #pragma unroll
      for (int m = 0; m < 4; ++m)
        #pragma unroll
        for (int kk = 0; kk < 2; ++kk)
          a[m][kk] = *(const bf16x8*)(lds + (kt * 8 + m * 2 + kk) * 1024 + l * 16);
      __builtin_amdgcn_s_setprio(1);
      #pragma unroll
      for (int kk = 0; kk < 2; ++kk)
        #pragma unroll
        for (int m = 0; m < 4; ++m)
          #pragma unroll
          for (int n = 0; n < 4; ++n)
            acc1[m][n] = __builtin_amdgcn_mfma_f32_16x16x32_bf16(
                b[n * 2 + kk], a[m][kk], acc1[m][n], 0, 0, 0);
      __builtin_amdgcn_s_setprio(0);
    }
    asm volatile("s_barrier" ::: "memory");     // protect h(j-1) readers
    #pragma unroll
    for (int m = 0; m < 4; ++m) {
      const int row = (m << 4) + lr;
      #pragma unroll
      for (int n = 0; n < 4; ++n) {
        f32x4 a4 = acc1[m][n] + *(const f32x4*)(b1 + g * 64 + (n << 4) + (lg << 2));
        bf16x4 c;
        #pragma unroll
        for (int r = 0; r < 4; ++r) {
          float vvv = a4[r];
          float y = vvv * (1.0f + 0.044715f * vvv * vvv);
          c[r] = (__bf16)(vvv / (1.0f + __expf(-1.5957691216057308f * y)));
        }
        const int ch = (n << 1) + (lg >> 1);
        *(bf16x4*)(hb + (row << 7) + ((ch ^ (row & 7)) << 4) + ((lg & 1) << 3)) = c;
      }
    }
    asm volatile("s_waitcnt lgkmcnt(0)" ::: "memory");
    __builtin_amdgcn_sched_barrier(0);
    asm volatile("s_barrier" ::: "memory");     // h(j) visible
    {
      bf16x8 bhA[12], bhB[12];
      LOADW2(bhA, j, 0)
      FC2_STEP(0, bhA, bhB)
      FC2_STEP(1, bhB, bhA)
      FC2_STEP(2, bhA, bhB)
      FC2_STEP(3, bhB, bhA)
    }
  }
#undef FC2_STEP
#undef LOADW2

  // epilogue: +b2 +s1(bf16) -> fp32 row-major
  const int col0 = w * 96;
  #pragma unroll
  for (int m = 0; m < 4; ++m) {
    const int grow = tok0 + (m << 4) + lr;
    #pragma unroll
    for (int n = 0; n < 6; ++n) {
      const int gcol = col0 + (n << 4) + (lg << 2);
      f32x4 a4 = acc2[m][n] + *(const f32x4*)(b2 + gcol);
      bf16x4 sv = *(const bf16x4*)(s1 + (size_t)grow * DIM + gcol);
      f32x4 o;
      #pragma unroll
      for (int r = 0; r < 4; ++r) o[r] = a4[r] + (float)sv[r];
      *(f32x4*)(outp + (size_t)grow * DIM + gcol) = o;
    }
  }
}

// ---------------- window attention: writes PACKED-A layout for proj --------
__global__ __launch_bounds__(64) void attn_k(const __bf16* __restrict__ qkv,
                                             const __bf16* __restrict__ vt,
                                             const float* __restrict__ pb,
                                             __bf16* __restrict__ outp) {
  __shared__ __align__(1024) char P[4096];
  const int l = threadIdx.x, lr = l & 15, lg = l >> 4;
  const int bid = blockIdx.x;
  const int xc = bid & 7, kk = bid >> 3;
  const int wh = (kk / 7) * 8 + xc, mi = kk % 7;
  const int win = wh / NHEADS, h = wh - win * NHEADS;
  const size_t wbase = (size_t)win * 98 * QKV_DIM;
  const __bf16* qb = qkv + wbase + h * 32;
  const __bf16* kb = qb + 384;
  const bf16x8 z8 = {};
  const f32x4 fz = {};

  bf16x8 kf[7];
  #pragma unroll
  for (int ni = 0; ni < 7; ++ni) {
    int tok = ni * 16 + lr;
    kf[ni] = (tok < 98) ? *(const bf16x8*)(kb + (size_t)tok * QKV_DIM + lg * 8) : z8;
  }
  int qt = mi * 16 + lr;
  bf16x8 qf = (qt < 98) ? *(const bf16x8*)(qb + (size_t)qt * QKV_DIM + lg * 8) : z8;
  const f32x4* pbp = (const f32x4*)pb + (size_t)((h * 7 + mi) * 7) * 64 + l;
  f32x4 bv[7];
  #pragma unroll
  for (int ni = 0; ni < 7; ++ni) bv[ni] = pbp[ni * 64];

  f32x4 s[7];
  #pragma unroll
  for (int ni = 0; ni < 7; ++ni)
    s[ni] = __builtin_amdgcn_mfma_f32_16x16x32_bf16(qf, kf[ni], fz, 0, 0, 0);

  if (l < 32) {
    int row = l >> 1, c = 14 + (l & 1);
    *(f32x4*)(P + row * 256 + ((c ^ (row & 7)) << 4)) = fz;
  }

  #pragma unroll
  for (int r = 0; r < 4; ++r) {
    float mx = -1e30f;
    #pragma unroll
    for (int ni = 0; ni < 7; ++ni) {
      float vv = s[ni][r] + bv[ni][r];
      s[ni][r] = vv;
      mx = fmaxf(mx, vv);
    }
    #pragma unroll
    for (int m2 = 1; m2 < 16; m2 <<= 1) mx = fmaxf(mx, __shfl_xor(mx, m2, 64));
    float sum = 0.f;
    #pragma unroll
    for (int ni = 0; ni < 7; ++ni) { float p = __expf(s[ni][r] - mx); s[ni][r] = p; sum += p; }
    #pragma unroll
    for (int m2 = 1; m2 < 16; m2 <<= 1) sum += __shfl_xor(sum, m2, 64);
    float inv = 1.0f / sum;
    int il = lg * 4 + r;
    #pragma unroll
    for (int ni = 0; ni < 7; ++ni) {
      int j = ni * 16 + lr;
      *(__bf16*)(P + il * 256 + (((j >> 3) ^ (il & 7)) << 4) + ((j & 7) << 1)) =
          (__bf16)(s[ni][r] * inv);
    }
  }
  __syncthreads();

  bf16x8 pa[4];
  #pragma unroll
  for (int ks = 0; ks < 4; ++ks) {
    int ck = ks * 4 + lg;
    pa[ks] = *(const bf16x8*)(P + lr * 256 + ((ck ^ (lr & 7)) << 4));
  }
  const __bf16* vrow = vt + ((size_t)wh * 32) * 128;
  f32x4 oo[2];
  #pragma unroll
  for (int nf = 0; nf < 2; ++nf) {
    int d = nf * 16 + lr;
    f32x4 o = fz;
    #pragma unroll
    for (int ks = 0; ks < 4; ++ks) {
      bf16x8 vb = *(const bf16x8*)(vrow + (size_t)d * 128 + ks * 32 + lg * 8);
      o = __builtin_amdgcn_mfma_f32_16x16x32_bf16(pa[ks], vb, o, 0, 0, 0);
    }
    oo[nf] = o;
  }
  #pragma unroll
  for (int nf = 0; nf < 2; ++nf)
    #pragma unroll
    for (int r = 0; r < 4; ++r)
      *(__bf16*)(P + (lg * 4 + r) * 64 + (((nf << 4) + lr) << 1)) = (__bf16)oo[nf][r];
  asm volatile("s_waitcnt lgkmcnt(0)" ::: "memory");
  __builtin_amdgcn_sched_barrier(0);
  {
    const int row = l >> 2;
    bf16x8 v = *(const bf16x8*)(P + row * 64 + ((l & 3) << 4));
    const int tok = mi * 16 + row;
    if (tok < 98) {
      const int tg = win * 98 + tok;                 // global window-major token
      const int o = (h << 2) + (l & 3);              // feature octet
      const int mg2 = tg >> 6, m2 = (tg >> 4) & 3, lr2 = tg & 15;
      const int kt = o >> 3, kk2 = (o >> 2) & 1, lg2 = o & 3;
      *(bf16x8*)(outp + (size_t)mg2 * 24576 +
                 ((size_t)((kt * 8 + m2 * 2 + kk2) * 64 + (lg2 << 4) + lr2)) * 8) = v;
    }
  }
}

// ---------------- launch ----------------
extern "C" void kernel_launch(void* const* d_in, const int* in_sizes, int n_in,
                              void* d_out, int out_size, void* d_ws, size_t ws_size,
                              hipStream_t stream) {
  const float* x      = (const float*)d_in[0];
  const float* n1g    = (const float*)d_in[1];
  const float* n1b    = (const float*)d_in[2];
  const float* qkv_w  = (const float*)d_in[3];
  const float* qkv_b  = (const float*)d_in[4];
  const float* proj_w = (const float*)d_in[5];
  const float* proj_b = (const float*)d_in[6];
  const float* btab   = (const float*)d_in[7];
  const float* n2g    = (const float*)d_in[8];
  const float* n2b    = (const float*)d_in[9];
  const float* fc1_w  = (const float*)d_in[10];
  const float* fc1_b  = (const float*)d_in[11];
  const float* fc2_w  = (const float*)d_in[12];
  const float* fc2_b  = (const float*)d_in[13];
  const int*   relidx = (const int*)d_in[14];
  float* outp = (float*)d_out;
  (void)in_sizes; (void)n_in; (void)out_size; (void)ws_size;

  char* ws = (char*)d_ws;
  size_t off = 0;
  auto alloc = [&](size_t bytes) {
    char* p = ws + off;
    off = (off + bytes + 255) & ~(size_t)255;
    return p;
  };
  int*    tokmap  = (int*)alloc((size_t)NTOK * 4);
  float*  biasex  = (float*)alloc((size_t)NHEADS * 49 * 256 * 4);
  __bf16* wqkvP   = (__bf16*)alloc((size_t)QKV_DIM * DIM * 2);
  __bf16* wprojP  = (__bf16*)alloc((size_t)DIM * DIM * 2);
  __bf16* wfc1P   = (__bf16*)alloc((size_t)HID * DIM * 2);
  __bf16* wfc2P   = (__bf16*)alloc((size_t)DIM * HID * 2);
  float*  qkvbS   = (float*)alloc((size_t)QKV_DIM * 4);
  __bf16* tokens  = (__bf16*)alloc((size_t)NTOK * DIM * 2);  // LN1-packed, later attn-packed
  __bf16* qkvbuf  = (__bf16*)alloc((size_t)NTOK * HID * 2);  // qkv row-major
  __bf16* s1      = (__bf16*)alloc((size_t)NTOK * DIM * 2);  // x + attn-proj, bf16
  __bf16* vt = (__bf16*)d_out;    // scratch in d_out until the fused MLP writes it

  const float scale = 0.17677669529663687f;  // 1/sqrt(32)

  build_tokmap_k<<<NTOK / 256, 256, 0, stream>>>(tokmap);
  expand_biasp_k<<<(NHEADS * 49 * 256) / 256, 256, 0, stream>>>(btab, relidx, biasex);
  pack_w64_k<<<(DIM * QKV_DIM / 8) / 256, 256, 0, stream>>>(qkv_w, wqkvP, DIM, QKV_DIM, 6, DIM, scale);
  pack_w64_k<<<(DIM * DIM / 8) / 256, 256, 0, stream>>>(proj_w, wprojP, DIM, DIM, 6, 0, 1.0f);
  pack_w64_k<<<(DIM * HID / 8) / 256, 256, 0, stream>>>(fc1_w, wfc1P, DIM, HID, 6, 0, 1.0f);
  pack_w96_k<<<(HID * DIM / 8) / 256, 256, 0, stream>>>(fc2_w, wfc2P);
  scale_bias_k<<<(QKV_DIM + 255) / 256, 256, 0, stream>>>(qkv_b, qkvbS, QKV_DIM, DIM, scale);

  ln_pack_k<float, true><<<NTOK / 32, 256, 0, stream>>>(x, n1g, n1b, tokens, tokmap);
  gemm_stream_k<0, 6><<<(NTOK / 256) * (QKV_DIM / 64), 256, 0, stream>>>(
      tokens, wqkvP, qkvbS, QKV_DIM, qkvbuf, nullptr, nullptr);
  vtrans_k<<<NWIN, 384, 0, stream>>>(qkvbuf, vt);
  attn_k<<<NWIN * NHEADS * 7, 64, 0, stream>>>(qkvbuf, vt, biasex, tokens);
  gemm_stream_k<1, 6><<<(NTOK / 256) * (DIM / 64), 256, 0, stream>>>(
      tokens, wprojP, proj_b, DIM, s1, x, tokmap);
  mlp_fused_k<<<NTOK / 64, 256, 0, stream>>>(
      s1, n2g, n2b, wfc1P, fc1_b, wfc2P, fc2_b, outp);
}